// Round 3
// baseline (282.544 us; speedup 1.0000x reference)
//
#include <hip/hip_runtime.h>
#include <math.h>

#define B_ 4
#define S_ 2048
#define D_ 512
#define H_ 8
#define HD_ 64
#define SZ_ (B_ * S_ * D_)
#define WSZ_ (D_ * D_)   // 262144
#define BSH_ (B_ * S_ * H_)

// 0.125 * log2(e): folds the 1/sqrt(64) score scale and exp->exp2 into Qh.
#define QSCALE_ 0.18033688011112042f

typedef _Float16 v4h __attribute__((ext_vector_type(4)));
typedef _Float16 v8h __attribute__((ext_vector_type(8)));
typedef float    v4f __attribute__((ext_vector_type(4)));

// Async global->LDS, 16B per lane. LDS dest must be wave-uniform base
// (HW adds lane*16); global source is per-lane.
__device__ __forceinline__ void gload16(const void* g, void* l) {
    __builtin_amdgcn_global_load_lds((__attribute__((address_space(1))) void*)g,
                                     (__attribute__((address_space(3))) void*)l,
                                     16, 0, 0);
}

__device__ __forceinline__ v8h pack8(v4f a, v4f b) {
    return __builtin_shufflevector(__builtin_convertvector(a, v4h),
                                   __builtin_convertvector(b, v4h),
                                   0, 1, 2, 3, 4, 5, 6, 7);
}

// ---------------------------------------------------------------------------
// R12: W[k][n] fp32 -> 8KB swizzled f16 blocks, 64 n-rows x 64 k each.
// block(mat, nt8, kc8): f16 idx r*64 + s*8 + j = W[kc*64 + (s^(r&7))*8 + j][nt*64 + r]
// The 8 kc-blocks of one nt are contiguous (64KB panel) so proj/outproj can
// stage a whole n-panel with linear global_load_lds and read with the XOR.
// ---------------------------------------------------------------------------
__global__ __launch_bounds__(256) void wtrans_kernel(const float* __restrict__ Wq,
                                                     const float* __restrict__ Wo,
                                                     _Float16* __restrict__ Wt) {
    __shared__ float Ts[64][68];   // [k-local][n-local]
    const int kc = blockIdx.x, nt = blockIdx.y, mat = blockIdx.z;
    const float* W = mat ? Wo : Wq;
    const int k0 = kc * 64, n0 = nt * 64;
    const int t = threadIdx.x;
#pragma unroll
    for (int i = 0; i < 4; i++) {
        int s2 = t + i * 256;
        int kk = s2 >> 4, nc = (s2 & 15) * 4;
        *(float4*)&Ts[kk][nc] = *(const float4*)&W[(size_t)(k0 + kk) * 512 + n0 + nc];
    }
    __syncthreads();
    _Float16* blk = Wt + (((size_t)mat * 8 + nt) * 8 + kc) * 4096;
#pragma unroll
    for (int i = 0; i < 2; i++) {
        int s2 = t + i * 256;
        int r = s2 >> 3, s = s2 & 7;
        int kl = (s ^ (r & 7)) * 8;
        v8h p;
#pragma unroll
        for (int j = 0; j < 8; j++) p[j] = (_Float16)Ts[kl + j][r];
        *(v8h*)&blk[r * 64 + s * 8] = p;
    }
}

// ---------------------------------------------------------------------------
// R13 proj: B-resident streaming GEMM (R12 structure, VT-permutation fixed).
// The whole 64x512 W-panel (64KB) is staged into LDS ONCE; after the single
// barrier the K-loop is barrier-free: A fragments load straight from global,
// convert in-register, MFMA. 2 blocks/CU (LDS-capped).
// z in {0,1,2} -> Qh (pre-scaled) / Kh / VT [B,H,HD,S(permuted)].
// VT key-permutation (required by flash PV 16x16x16 MFMAs): within each
// 32-pos block, pos = quad*8 + mi*4 + r holds key mi*16 + quad*4 + r.
// ---------------------------------------------------------------------------
__global__ __launch_bounds__(256) void proj_mfma(const float* __restrict__ q,
                                                 const float* __restrict__ kin,
                                                 const float* __restrict__ v,
                                                 const _Float16* __restrict__ Wt,
                                                 const float* __restrict__ bq,
                                                 _Float16* __restrict__ Qh,
                                                 _Float16* __restrict__ Kh,
                                                 _Float16* __restrict__ VT) {
    __shared__ __align__(16) _Float16 Bs[32768];   // 64 n-rows x 512 k, swizzled
    const int dblk = blockIdx.x;                   // 768 blocks
    const int xcd = dblk & 7, ii = dblk >> 3;      // assume XCD = d%8 round-robin
    const int nt = ii & 7;
    const int g  = ((ii >> 3) << 3) | xcd;         // 0..95 (z, m-chunk), XCD-grouped
    const int z  = g >> 5;
    const int m0 = (g & 31) * 256;
    const float* X = (z == 0) ? q : ((z == 1) ? kin : v);
    const int t = threadIdx.x;
    const int lane = t & 63, w = t >> 6;
    const int quad = lane >> 4, l16 = lane & 15;

    // Stage the whole B panel (64KB) once.
    const _Float16* psrc = Wt + (size_t)nt * 32768 + ((size_t)w * 64 + lane) * 8;
    _Float16* pdst = &Bs[(size_t)w * 512];
#pragma unroll
    for (int j = 0; j < 16; j++)
        gload16(psrc + j * 2048, pdst + j * 2048);
    __syncthreads();   // the only barrier in the kernel

    for (int pass = 0; pass < 2; ++pass) {
        const int r0 = m0 + pass * 128 + w * 32;
        const float* A0 = X + (size_t)(r0 + l16) * 512 + quad * 8;
        const float* A1 = A0 + 16 * 512;

        v4f acc[2][4];
#pragma unroll
        for (int mi = 0; mi < 2; mi++)
#pragma unroll
            for (int ni = 0; ni < 4; ni++) acc[mi][ni] = (v4f)0.f;

#pragma unroll
        for (int kc = 0; kc < 8; ++kc) {
#pragma unroll
            for (int ks = 0; ks < 2; ++ks) {
                const int ko = kc * 64 + ks * 32;
                v8h af0 = pack8(*(const v4f*)(A0 + ko), *(const v4f*)(A0 + ko + 4));
                v8h af1 = pack8(*(const v4f*)(A1 + ko), *(const v4f*)(A1 + ko + 4));
                const int sx = ks * 32 + quad * 8;
#pragma unroll
                for (int ni = 0; ni < 4; ++ni) {
                    const int rb = ni * 16 + l16;
                    v8h bf = *(const v8h*)&Bs[kc * 4096 + rb * 64 + (sx ^ ((rb & 7) * 8))];
                    acc[0][ni] = __builtin_amdgcn_mfma_f32_16x16x32_f16(af0, bf, acc[0][ni], 0, 0, 0);
                    acc[1][ni] = __builtin_amdgcn_mfma_f32_16x16x32_f16(af1, bf, acc[1][ni], 0, 0, 0);
                }
            }
        }

        if (z < 2) {
            _Float16* Y = z ? Kh : Qh;
            const float sc = z ? 1.f : QSCALE_;
#pragma unroll
            for (int mi = 0; mi < 2; mi++) {
                int mb = r0 + mi * 16 + quad * 4;
#pragma unroll
                for (int ni = 0; ni < 4; ni++) {
                    int n = nt * 64 + ni * 16 + l16;
                    float bj = bq[n];
#pragma unroll
                    for (int r = 0; r < 4; r++)
                        Y[(size_t)(mb + r) * 512 + n] = (_Float16)((acc[mi][ni][r] + bj) * sc);
                }
            }
        } else {
            const int b = r0 >> 11;
#pragma unroll
            for (int mi = 0; mi < 2; mi++) {
                // key-permuted s-position (see header comment): NOT identity.
                int pos = (r0 & 2047) + quad * 8 + mi * 4;
#pragma unroll
                for (int ni = 0; ni < 4; ni++) {
                    int n = nt * 64 + ni * 16 + l16;
                    float bj = bq[n];
                    v4h pk;
#pragma unroll
                    for (int r = 0; r < 4; r++) pk[r] = (_Float16)(acc[mi][ni][r] + bj);
                    *(v4h*)&VT[(((size_t)b * H_ + nt) * HD_ + ni * 16 + l16) * S_ + pos] = pk;
                }
            }
        }
    }
}

// ---------------------------------------------------------------------------
// R12 outproj: B-resident streaming structure, split-K combine (O1+O2)*1/l
// fused into the A-fragment build. Per-row/per-head rcp hoisted per 32-row
// tile. Grid 256 (1 block/CU), single barrier.
// ---------------------------------------------------------------------------
__global__ __launch_bounds__(256) void outproj_mfma(const float* __restrict__ Op,
                                                    const float* __restrict__ lp,
                                                    const _Float16* __restrict__ Wt,
                                                    const float* __restrict__ bo,
                                                    float* __restrict__ out) {
    __shared__ __align__(16) _Float16 Bs[32768];
    const int dblk = blockIdx.x;                   // 256 blocks
    const int xcd = dblk & 7, ii = dblk >> 3;
    const int nt = ii & 7;
    const int mc = ((ii >> 3) << 3) | xcd;         // 0..31
    const int m0 = mc * 256;
    const int t = threadIdx.x;
    const int lane = t & 63, w = t >> 6;
    const int quad = lane >> 4, l16 = lane & 15;

    const _Float16* psrc = Wt + (size_t)(8 + nt) * 32768 + ((size_t)w * 64 + lane) * 8;
    _Float16* pdst = &Bs[(size_t)w * 512];
#pragma unroll
    for (int j = 0; j < 16; j++)
        gload16(psrc + j * 2048, pdst + j * 2048);
    __syncthreads();

    for (int pass = 0; pass < 2; ++pass) {
        const int r0 = m0 + pass * 128 + w * 32;
        const float* P0 = Op + (size_t)(r0 + l16) * 512 + quad * 8;
        const float* P1 = P0 + 16 * 512;
        const float* Q0 = P0 + SZ_;
        const float* Q1 = P1 + SZ_;
        const float* lp0 = lp + (size_t)(r0 + l16) * 8;
        const float* lp1 = lp0 + 16 * 8;

        float linv0[8], linv1[8];
#pragma unroll
        for (int kc = 0; kc < 8; kc++) {
            linv0[kc] = __builtin_amdgcn_rcpf(lp0[kc] + lp0[BSH_ + kc]);
            linv1[kc] = __builtin_amdgcn_rcpf(lp1[kc] + lp1[BSH_ + kc]);
        }

        v4f acc[2][4];
#pragma unroll
        for (int mi = 0; mi < 2; mi++)
#pragma unroll
            for (int ni = 0; ni < 4; ni++) acc[mi][ni] = (v4f)0.f;

#pragma unroll
        for (int kc = 0; kc < 8; ++kc) {
#pragma unroll
            for (int ks = 0; ks < 2; ++ks) {
                const int ko = kc * 64 + ks * 32;
                v4f s00 = (*(const v4f*)(P0 + ko) + *(const v4f*)(Q0 + ko)) * linv0[kc];
                v4f s01 = (*(const v4f*)(P0 + ko + 4) + *(const v4f*)(Q0 + ko + 4)) * linv0[kc];
                v4f s10 = (*(const v4f*)(P1 + ko) + *(const v4f*)(Q1 + ko)) * linv1[kc];
                v4f s11 = (*(const v4f*)(P1 + ko + 4) + *(const v4f*)(Q1 + ko + 4)) * linv1[kc];
                v8h af0 = pack8(s00, s01);
                v8h af1 = pack8(s10, s11);
                const int sx = ks * 32 + quad * 8;
#pragma unroll
                for (int ni = 0; ni < 4; ++ni) {
                    const int rb = ni * 16 + l16;
                    v8h bf = *(const v8h*)&Bs[kc * 4096 + rb * 64 + (sx ^ ((rb & 7) * 8))];
                    acc[0][ni] = __builtin_amdgcn_mfma_f32_16x16x32_f16(af0, bf, acc[0][ni], 0, 0, 0);
                    acc[1][ni] = __builtin_amdgcn_mfma_f32_16x16x32_f16(af1, bf, acc[1][ni], 0, 0, 0);
                }
            }
        }

#pragma unroll
        for (int mi = 0; mi < 2; mi++) {
            int mb = r0 + mi * 16 + quad * 4;
#pragma unroll
            for (int ni = 0; ni < 4; ni++) {
                int n = nt * 64 + ni * 16 + l16;
                float bj = bo[n];
#pragma unroll
                for (int r = 0; r < 4; r++)
                    out[(size_t)(mb + r) * 512 + n] = acc[mi][ni][r] + bj;
            }
        }
    }
}

// ---------------------------------------------------------------------------
// Split-K MFMA f16 flash attention (FROZEN from R8: 57.9 µs verified).
// ---------------------------------------------------------------------------
__global__ __launch_bounds__(256) void flash_attn_f16(const _Float16* __restrict__ Qh,
                                                      const _Float16* __restrict__ Kh,
                                                      const _Float16* __restrict__ VT,
                                                      float* __restrict__ Op,
                                                      float* __restrict__ lp) {
    __shared__ _Float16 Ks[128 * 72];    // [key][d], pad 72
    __shared__ _Float16 Vs[64 * 136];    // [d][pos], pad 136

    const int t     = threadIdx.x;
    const int lane  = t & 63;
    const int w     = t >> 6;
    const int quad  = lane >> 4;
    const int l16   = lane & 15;
    const int q0    = blockIdx.x * 128;
    const int h     = blockIdx.y;
    const int b     = blockIdx.z >> 1;
    const int split = blockIdx.z & 1;

    const size_t base  = (size_t)b * S_ * D_ + (size_t)h * HD_;
    const size_t vbase = ((size_t)b * H_ + h) * HD_ * (size_t)S_;

    v8h qf[2][2];
#pragma unroll
    for (int nb = 0; nb < 2; nb++) {
        const _Float16* qrow = Qh + base + (size_t)(q0 + w * 32 + nb * 16 + l16) * D_;
        qf[nb][0] = *(const v8h*)(qrow + quad * 8);
        qf[nb][1] = *(const v8h*)(qrow + 32 + quad * 8);
    }

    v4f o[2][4];
#pragma unroll
    for (int nb = 0; nb < 2; nb++)
#pragma unroll
        for (int i = 0; i < 4; i++) o[nb][i] = (v4f)0.f;
    float l_lane[2] = {0.f, 0.f};

    const int kbeg = split * (S_ / 2);
    const int kend = kbeg + S_ / 2;

    v8h kv[4], vv[4];
#define LOADKV(kk)                                                             \
    do {                                                                       \
        _Pragma("unroll") for (int i = 0; i < 4; i++) {                        \
            int c = t + i * 256;                                               \
            kv[i] = *(const v8h*)(Kh + base + (size_t)((kk) + (c >> 3)) * D_ + (c & 7) * 8); \
            vv[i] = *(const v8h*)(VT + vbase + (size_t)(c >> 4) * S_ + (kk) + (c & 15) * 8); \
        }                                                                      \
    } while (0)

    LOADKV(kbeg);

    for (int kk0 = kbeg; kk0 < kend; kk0 += 128) {
        __syncthreads();
#pragma unroll
        for (int i = 0; i < 4; i++) {
            int c = t + i * 256;
            *(v8h*)&Ks[(c >> 3) * 72 + (c & 7) * 8] = kv[i];
            *(v8h*)&Vs[(c >> 4) * 136 + (c & 15) * 8] = vv[i];
        }
        __syncthreads();

        if (kk0 + 128 < kend) LOADKV(kk0 + 128);

#pragma unroll
        for (int hh = 0; hh < 2; hh++) {
            v4f sc[4][2];
#pragma unroll
            for (int mb = 0; mb < 4; mb++)
#pragma unroll
                for (int nb = 0; nb < 2; nb++) sc[mb][nb] = (v4f)0.f;
#pragma unroll
            for (int ks = 0; ks < 2; ks++) {
#pragma unroll
                for (int mb = 0; mb < 4; mb++) {
                    v8h ak = *(const v8h*)&Ks[(hh * 64 + mb * 16 + l16) * 72 + ks * 32 + quad * 8];
#pragma unroll
                    for (int nb = 0; nb < 2; nb++)
                        sc[mb][nb] = __builtin_amdgcn_mfma_f32_16x16x32_f16(ak, qf[nb][ks], sc[mb][nb], 0, 0, 0);
                }
            }

            v4h pf[4][2];
#pragma unroll
            for (int nb = 0; nb < 2; nb++) {
#pragma unroll
                for (int mb = 0; mb < 4; mb++) {
                    v4f pv;
#pragma unroll
                    for (int r = 0; r < 4; r++) pv[r] = __builtin_amdgcn_exp2f(sc[mb][nb][r]);
                    pf[mb][nb] = __builtin_convertvector(pv, v4h);
                    l_lane[nb] += (pv[0] + pv[1]) + (pv[2] + pv[3]);
                }
            }

#pragma unroll
            for (int p = 0; p < 2; p++) {
#pragma unroll
                for (int dblk = 0; dblk < 4; dblk++) {
                    v8h vf2 = *(const v8h*)&Vs[(dblk * 16 + l16) * 136 + hh * 64 + p * 32 + quad * 8];
                    v4h vlo = __builtin_shufflevector(vf2, vf2, 0, 1, 2, 3);
                    v4h vhi = __builtin_shufflevector(vf2, vf2, 4, 5, 6, 7);
#pragma unroll
                    for (int nb = 0; nb < 2; nb++) {
                        o[nb][dblk] = __builtin_amdgcn_mfma_f32_16x16x16f16(vlo, pf[2 * p][nb], o[nb][dblk], 0, 0, 0);
                        o[nb][dblk] = __builtin_amdgcn_mfma_f32_16x16x16f16(vhi, pf[2 * p + 1][nb], o[nb][dblk], 0, 0, 0);
                    }
                }
            }
        }
    }
#undef LOADKV

    float* Ops = Op + (size_t)split * SZ_;
#pragma unroll
    for (int nb = 0; nb < 2; nb++) {
        float rs = l_lane[nb];
        rs += __shfl_xor(rs, 16);
        rs += __shfl_xor(rs, 32);
        int qrow = q0 + w * 32 + nb * 16 + l16;
        if (quad == 0)
            lp[(size_t)split * BSH_ + ((size_t)b * S_ + qrow) * H_ + h] = rs;
        const size_t rbase = base + (size_t)qrow * D_;
#pragma unroll
        for (int dblk = 0; dblk < 4; dblk++)
            *(v4f*)&Ops[rbase + dblk * 16 + quad * 4] = o[nb][dblk];
    }
}

extern "C" void kernel_launch(void* const* d_in, const int* in_sizes, int n_in,
                              void* d_out, int out_size, void* d_ws, size_t ws_size,
                              hipStream_t stream) {
    const float* query = (const float*)d_in[0];
    const float* key   = (const float*)d_in[1];
    const float* value = (const float*)d_in[2];
    const float* Wq    = (const float*)d_in[3];
    const float* bq    = (const float*)d_in[4];
    const float* Wo    = (const float*)d_in[5];
    const float* bo    = (const float*)d_in[6];
    float* out = (float*)d_out;

    _Float16* ws = (_Float16*)d_ws;
    _Float16* Qh = ws;                                   // [B,S,D] f16
    _Float16* Kh = ws + (size_t)SZ_;                     // [B,S,D] f16
    _Float16* VT = ws + 2 * (size_t)SZ_;                 // [B,H,HD,S] f16 (permuted)
    _Float16* Wt = ws + 3 * (size_t)SZ_;                 // 2x[8 nt][8 kc][64x64 swz] f16
    float*    Op = (float*)(ws + 3 * (size_t)SZ_ + 2 * (size_t)WSZ_);  // 2x[B,S,D] f32
    float*    lp = Op + 2 * (size_t)SZ_;                 // 2x[B,S,H] f32

    wtrans_kernel<<<dim3(8, 8, 2), 256, 0, stream>>>(Wq, Wo, Wt);
    proj_mfma<<<dim3(768), 256, 0, stream>>>(query, key, value, Wt, bq, Qh, Kh, VT);
    flash_attn_f16<<<dim3(S_ / 128, H_, B_ * 2), 256, 0, stream>>>(Qh, Kh, VT, Op, lp);
    outproj_mfma<<<dim3(256), 256, 0, stream>>>(Op, lp, Wt, bo, out);
}

// Round 4
// 201.995 us; speedup vs baseline: 1.3988x; 1.3988x over previous
//
#include <hip/hip_runtime.h>
#include <math.h>

#define B_ 4
#define S_ 2048
#define D_ 512
#define H_ 8
#define HD_ 64
#define SZ_ (B_ * S_ * D_)
#define WSZ_ (D_ * D_)   // 262144
#define BSH_ (B_ * S_ * H_)

// 0.125 * log2(e): folds the 1/sqrt(64) score scale and exp->exp2 into Qh.
#define QSCALE_ 0.18033688011112042f

typedef _Float16 v4h __attribute__((ext_vector_type(4)));
typedef _Float16 v8h __attribute__((ext_vector_type(8)));
typedef float    v4f __attribute__((ext_vector_type(4)));

// Async global->LDS, 16B per lane. LDS dest must be wave-uniform base
// (HW adds lane*16); global source is per-lane.
__device__ __forceinline__ void gload16(const void* g, void* l) {
    __builtin_amdgcn_global_load_lds((__attribute__((address_space(1))) void*)g,
                                     (__attribute__((address_space(3))) void*)l,
                                     16, 0, 0);
}

__device__ __forceinline__ v8h pack8(v4f a, v4f b) {
    return __builtin_shufflevector(__builtin_convertvector(a, v4h),
                                   __builtin_convertvector(b, v4h),
                                   0, 1, 2, 3, 4, 5, 6, 7);
}

// ---------------------------------------------------------------------------
// W[k][n] fp32 -> 16KB swizzled f16 blocks, 128 n-rows x 64 k each.
// block(mat, nt4, kc8): f16 idx r*64 + s*8 + j = W[kc*64 + (s^(r&7))*8 + j][nt*128 + r]
// (verbatim from the R11-verified build.)
// ---------------------------------------------------------------------------
__global__ __launch_bounds__(256) void wtrans_kernel(const float* __restrict__ Wq,
                                                     const float* __restrict__ Wo,
                                                     _Float16* __restrict__ Wt) {
    __shared__ float Ts[64][132];
    const int kc = blockIdx.x, nt = blockIdx.y, mat = blockIdx.z;
    const float* W = mat ? Wo : Wq;
    const int k0 = kc * 64, n0 = nt * 128;
    const int t = threadIdx.x;
#pragma unroll
    for (int i = 0; i < 8; i++) {
        int s2 = t + i * 256;
        int kk = s2 >> 5, nc = (s2 & 31) * 4;
        *(float4*)&Ts[kk][nc] = *(const float4*)&W[(size_t)(k0 + kk) * 512 + n0 + nc];
    }
    __syncthreads();
    _Float16* blk = Wt + (((size_t)mat * 4 + nt) * 8 + kc) * 8192;
#pragma unroll
    for (int i = 0; i < 4; i++) {
        int s2 = t + i * 256;
        int r = s2 >> 3, s = s2 & 7;
        int kl = (s ^ (r & 7)) * 8;
        v8h p;
#pragma unroll
        for (int j = 0; j < 8; j++) p[j] = (_Float16)Ts[kl + j][r];
        *(v8h*)&blk[r * 64 + s * 8] = p;
    }
}

// ---------------------------------------------------------------------------
// R14: q/k/v fp32 -> Xh f16 in blocked-swizzled layout [z][mt64][kc8][128x64].
// Within a block: f16 idx r*64 + (s^(r&7))*8 + j = X[mt*128+r][kc*64 + s*8 + j].
// Pure streaming; enables pure-f16 GEMM staging via global_load_lds.
// ---------------------------------------------------------------------------
__global__ __launch_bounds__(256) void convert_f16(const float* __restrict__ q,
                                                   const float* __restrict__ k,
                                                   const float* __restrict__ v,
                                                   _Float16* __restrict__ Xh) {
    const int kc = blockIdx.x, mt = blockIdx.y, z = blockIdx.z;
    const float* X = (z == 0) ? q : ((z == 1) ? k : v);
    _Float16* blk = Xh + (size_t)z * SZ_ + ((size_t)mt * 8 + kc) * 8192;
    const int t = threadIdx.x;
#pragma unroll
    for (int i = 0; i < 4; i++) {
        int s2 = t + i * 256;
        int r = s2 >> 3, s = s2 & 7;
        const float* src = X + (size_t)(mt * 128 + r) * 512 + kc * 64 + s * 8;
        *(v8h*)&blk[r * 64 + ((s ^ (r & 7)) * 8)] =
            pack8(*(const v4f*)src, *(const v4f*)(src + 4));
    }
}

// ---------------------------------------------------------------------------
// R14: split-K combine (O1+O2)*1/l -> Ah f16, same blocked-swizzled layout
// [mt64][kc8][128x64]. kc == head (64-col chunks align with heads).
// ---------------------------------------------------------------------------
__global__ __launch_bounds__(256) void combine_kernel(const float* __restrict__ Op,
                                                      const float* __restrict__ lp,
                                                      _Float16* __restrict__ Ah) {
    const int kc = blockIdx.x, mt = blockIdx.y;
    _Float16* blk = Ah + ((size_t)mt * 8 + kc) * 8192;
    const int t = threadIdx.x;
#pragma unroll
    for (int i = 0; i < 4; i++) {
        int s2 = t + i * 256;
        int r = s2 >> 3, s = s2 & 7;
        size_t row = (size_t)mt * 128 + r;
        const float* p = Op + row * 512 + kc * 64 + s * 8;
        const float* p2 = p + SZ_;
        float linv = __builtin_amdgcn_rcpf(lp[row * 8 + kc] + lp[BSH_ + row * 8 + kc]);
        v4f sa = (*(const v4f*)p + *(const v4f*)p2) * linv;
        v4f sb = (*(const v4f*)(p + 4) + *(const v4f*)(p2 + 4)) * linv;
        *(v8h*)&blk[r * 64 + ((s ^ (r & 7)) * 8)] = pack8(sa, sb);
    }
}

// ---------------------------------------------------------------------------
// R14 proj: m97-shaped pure-f16 GEMM. 128x128 tile, BK=64, 4 waves (2x2),
// BOTH operands staged per K-step via global_load_lds from pre-swizzled
// blocks (no VGPR round-trip, no fp32->f16 in the loop), 32KB LDS
// (~3 blocks/CU), 2 barriers/iter. Frag reads use the XOR (0 conflicts,
// verified R13). Epilogues verbatim from the R11-verified kernel.
// z in {0,1,2} -> Qh (pre-scaled) / Kh / VT [B,H,HD,S(permuted)].
// ---------------------------------------------------------------------------
__global__ __launch_bounds__(256) void proj_mfma(const _Float16* __restrict__ Xh,
                                                 const _Float16* __restrict__ Wt,
                                                 const float* __restrict__ bq,
                                                 _Float16* __restrict__ Qh,
                                                 _Float16* __restrict__ Kh,
                                                 _Float16* __restrict__ VT) {
    __shared__ __align__(16) _Float16 As[8192];
    __shared__ __align__(16) _Float16 Bs[8192];
    const int nt = blockIdx.x, mt = blockIdx.y, z = blockIdx.z;
    const int n0 = nt * 128, m0 = mt * 128;
    const int t = threadIdx.x, lane = t & 63, w = t >> 6;
    const int wm = w >> 1, wn = w & 1;
    const int quad = lane >> 4, l16 = lane & 15;

    const _Float16* Ab = Xh + (size_t)z * SZ_ + ((size_t)mt * 8) * 8192 + w * 512 + lane * 8;
    const _Float16* Bb = Wt + ((size_t)nt * 8) * 8192 + w * 512 + lane * 8;
    _Float16* Ad = As + w * 512;
    _Float16* Bd = Bs + w * 512;

    v4f acc[4][4];
#pragma unroll
    for (int mi = 0; mi < 4; mi++)
#pragma unroll
        for (int ni = 0; ni < 4; ni++) acc[mi][ni] = (v4f)0.f;

    for (int kc = 0; kc < 8; ++kc) {
        __syncthreads();   // prev iter's frag reads complete
#pragma unroll
        for (int i = 0; i < 4; i++) {
            gload16(Ab + kc * 8192 + i * 2048, Ad + i * 2048);
            gload16(Bb + kc * 8192 + i * 2048, Bd + i * 2048);
        }
        __syncthreads();   // vmcnt drained -> LDS tiles ready

#pragma unroll
        for (int ks = 0; ks < 2; ++ks) {
            const int sxx = (ks * 32 + quad * 8) ^ ((l16 & 7) * 8);
            v8h af[4], bf[4];
#pragma unroll
            for (int mi = 0; mi < 4; mi++)
                af[mi] = *(const v8h*)&As[(wm * 64 + mi * 16 + l16) * 64 + sxx];
#pragma unroll
            for (int ni = 0; ni < 4; ni++)
                bf[ni] = *(const v8h*)&Bs[(wn * 64 + ni * 16 + l16) * 64 + sxx];
#pragma unroll
            for (int mi = 0; mi < 4; mi++)
#pragma unroll
                for (int ni = 0; ni < 4; ni++)
                    acc[mi][ni] = __builtin_amdgcn_mfma_f32_16x16x32_f16(af[mi], bf[ni], acc[mi][ni], 0, 0, 0);
        }
    }

    if (z < 2) {
        _Float16* Y = z ? Kh : Qh;
        const float sc = z ? 1.f : QSCALE_;
#pragma unroll
        for (int mi = 0; mi < 4; mi++) {
            int mb = m0 + wm * 64 + mi * 16 + quad * 4;
#pragma unroll
            for (int ni = 0; ni < 4; ni++) {
                int n = n0 + wn * 64 + ni * 16 + l16;
                float bj = bq[n];
#pragma unroll
                for (int r = 0; r < 4; r++)
                    Y[(size_t)(mb + r) * 512 + n] = (_Float16)((acc[mi][ni][r] + bj) * sc);
            }
        }
    } else {
#pragma unroll
        for (int mi = 0; mi < 4; mi++) {
            int tile0 = (m0 & 2047) + wm * 64;
            int pos = tile0 + (mi >> 1) * 32 + quad * 8 + (mi & 1) * 4;
            int b = m0 >> 11;
#pragma unroll
            for (int ni = 0; ni < 4; ni++) {
                int n = n0 + wn * 64 + ni * 16 + l16;
                int h = n >> 6, dd = n & 63;
                float bj = bq[n];
                v4h pk;
#pragma unroll
                for (int r = 0; r < 4; r++) pk[r] = (_Float16)(acc[mi][ni][r] + bj);
                *(v4h*)&VT[(((size_t)b * H_ + h) * HD_ + dd) * S_ + pos] = pk;
            }
        }
    }
}

// ---------------------------------------------------------------------------
// R14 outproj: identical m97-shaped GEMM; A = Ah (combine output, blocked-
// swizzled f16), B = Wo panel (mat 1), epilogue adds bo, writes fp32 out.
// ---------------------------------------------------------------------------
__global__ __launch_bounds__(256) void outproj_mfma(const _Float16* __restrict__ Ah,
                                                    const _Float16* __restrict__ Wt,
                                                    const float* __restrict__ bo,
                                                    float* __restrict__ out) {
    __shared__ __align__(16) _Float16 As[8192];
    __shared__ __align__(16) _Float16 Bs[8192];
    const int nt = blockIdx.x, mt = blockIdx.y;
    const int n0 = nt * 128, m0 = mt * 128;
    const int t = threadIdx.x, lane = t & 63, w = t >> 6;
    const int wm = w >> 1, wn = w & 1;
    const int quad = lane >> 4, l16 = lane & 15;

    const _Float16* Ab = Ah + ((size_t)mt * 8) * 8192 + w * 512 + lane * 8;
    const _Float16* Bb = Wt + (size_t)(4 + nt) * 8 * 8192 + w * 512 + lane * 8;
    _Float16* Ad = As + w * 512;
    _Float16* Bd = Bs + w * 512;

    v4f acc[4][4];
#pragma unroll
    for (int mi = 0; mi < 4; mi++)
#pragma unroll
        for (int ni = 0; ni < 4; ni++) acc[mi][ni] = (v4f)0.f;

    for (int kc = 0; kc < 8; ++kc) {
        __syncthreads();
#pragma unroll
        for (int i = 0; i < 4; i++) {
            gload16(Ab + kc * 8192 + i * 2048, Ad + i * 2048);
            gload16(Bb + kc * 8192 + i * 2048, Bd + i * 2048);
        }
        __syncthreads();

#pragma unroll
        for (int ks = 0; ks < 2; ++ks) {
            const int sxx = (ks * 32 + quad * 8) ^ ((l16 & 7) * 8);
            v8h af[4], bf[4];
#pragma unroll
            for (int mi = 0; mi < 4; mi++)
                af[mi] = *(const v8h*)&As[(wm * 64 + mi * 16 + l16) * 64 + sxx];
#pragma unroll
            for (int ni = 0; ni < 4; ni++)
                bf[ni] = *(const v8h*)&Bs[(wn * 64 + ni * 16 + l16) * 64 + sxx];
#pragma unroll
            for (int mi = 0; mi < 4; mi++)
#pragma unroll
                for (int ni = 0; ni < 4; ni++)
                    acc[mi][ni] = __builtin_amdgcn_mfma_f32_16x16x32_f16(af[mi], bf[ni], acc[mi][ni], 0, 0, 0);
        }
    }

#pragma unroll
    for (int mi = 0; mi < 4; mi++) {
        int mb = m0 + wm * 64 + mi * 16 + quad * 4;
#pragma unroll
        for (int ni = 0; ni < 4; ni++) {
            int n = n0 + wn * 64 + ni * 16 + l16;
            float bj = bo[n];
#pragma unroll
            for (int r = 0; r < 4; r++)
                out[(size_t)(mb + r) * 512 + n] = acc[mi][ni][r] + bj;
        }
    }
}

// ---------------------------------------------------------------------------
// Split-K MFMA f16 flash attention (FROZEN from R8: 57.9 µs verified).
// ---------------------------------------------------------------------------
__global__ __launch_bounds__(256) void flash_attn_f16(const _Float16* __restrict__ Qh,
                                                      const _Float16* __restrict__ Kh,
                                                      const _Float16* __restrict__ VT,
                                                      float* __restrict__ Op,
                                                      float* __restrict__ lp) {
    __shared__ _Float16 Ks[128 * 72];    // [key][d], pad 72
    __shared__ _Float16 Vs[64 * 136];    // [d][pos], pad 136

    const int t     = threadIdx.x;
    const int lane  = t & 63;
    const int w     = t >> 6;
    const int quad  = lane >> 4;
    const int l16   = lane & 15;
    const int q0    = blockIdx.x * 128;
    const int h     = blockIdx.y;
    const int b     = blockIdx.z >> 1;
    const int split = blockIdx.z & 1;

    const size_t base  = (size_t)b * S_ * D_ + (size_t)h * HD_;
    const size_t vbase = ((size_t)b * H_ + h) * HD_ * (size_t)S_;

    v8h qf[2][2];
#pragma unroll
    for (int nb = 0; nb < 2; nb++) {
        const _Float16* qrow = Qh + base + (size_t)(q0 + w * 32 + nb * 16 + l16) * D_;
        qf[nb][0] = *(const v8h*)(qrow + quad * 8);
        qf[nb][1] = *(const v8h*)(qrow + 32 + quad * 8);
    }

    v4f o[2][4];
#pragma unroll
    for (int nb = 0; nb < 2; nb++)
#pragma unroll
        for (int i = 0; i < 4; i++) o[nb][i] = (v4f)0.f;
    float l_lane[2] = {0.f, 0.f};

    const int kbeg = split * (S_ / 2);
    const int kend = kbeg + S_ / 2;

    v8h kv[4], vv[4];
#define LOADKV(kk)                                                             \
    do {                                                                       \
        _Pragma("unroll") for (int i = 0; i < 4; i++) {                        \
            int c = t + i * 256;                                               \
            kv[i] = *(const v8h*)(Kh + base + (size_t)((kk) + (c >> 3)) * D_ + (c & 7) * 8); \
            vv[i] = *(const v8h*)(VT + vbase + (size_t)(c >> 4) * S_ + (kk) + (c & 15) * 8); \
        }                                                                      \
    } while (0)

    LOADKV(kbeg);

    for (int kk0 = kbeg; kk0 < kend; kk0 += 128) {
        __syncthreads();
#pragma unroll
        for (int i = 0; i < 4; i++) {
            int c = t + i * 256;
            *(v8h*)&Ks[(c >> 3) * 72 + (c & 7) * 8] = kv[i];
            *(v8h*)&Vs[(c >> 4) * 136 + (c & 15) * 8] = vv[i];
        }
        __syncthreads();

        if (kk0 + 128 < kend) LOADKV(kk0 + 128);

#pragma unroll
        for (int hh = 0; hh < 2; hh++) {
            v4f sc[4][2];
#pragma unroll
            for (int mb = 0; mb < 4; mb++)
#pragma unroll
                for (int nb = 0; nb < 2; nb++) sc[mb][nb] = (v4f)0.f;
#pragma unroll
            for (int ks = 0; ks < 2; ks++) {
#pragma unroll
                for (int mb = 0; mb < 4; mb++) {
                    v8h ak = *(const v8h*)&Ks[(hh * 64 + mb * 16 + l16) * 72 + ks * 32 + quad * 8];
#pragma unroll
                    for (int nb = 0; nb < 2; nb++)
                        sc[mb][nb] = __builtin_amdgcn_mfma_f32_16x16x32_f16(ak, qf[nb][ks], sc[mb][nb], 0, 0, 0);
                }
            }

            v4h pf[4][2];
#pragma unroll
            for (int nb = 0; nb < 2; nb++) {
#pragma unroll
                for (int mb = 0; mb < 4; mb++) {
                    v4f pv;
#pragma unroll
                    for (int r = 0; r < 4; r++) pv[r] = __builtin_amdgcn_exp2f(sc[mb][nb][r]);
                    pf[mb][nb] = __builtin_convertvector(pv, v4h);
                    l_lane[nb] += (pv[0] + pv[1]) + (pv[2] + pv[3]);
                }
            }

#pragma unroll
            for (int p = 0; p < 2; p++) {
#pragma unroll
                for (int dblk = 0; dblk < 4; dblk++) {
                    v8h vf2 = *(const v8h*)&Vs[(dblk * 16 + l16) * 136 + hh * 64 + p * 32 + quad * 8];
                    v4h vlo = __builtin_shufflevector(vf2, vf2, 0, 1, 2, 3);
                    v4h vhi = __builtin_shufflevector(vf2, vf2, 4, 5, 6, 7);
#pragma unroll
                    for (int nb = 0; nb < 2; nb++) {
                        o[nb][dblk] = __builtin_amdgcn_mfma_f32_16x16x16f16(vlo, pf[2 * p][nb], o[nb][dblk], 0, 0, 0);
                        o[nb][dblk] = __builtin_amdgcn_mfma_f32_16x16x16f16(vhi, pf[2 * p + 1][nb], o[nb][dblk], 0, 0, 0);
                    }
                }
            }
        }
    }
#undef LOADKV

    float* Ops = Op + (size_t)split * SZ_;
#pragma unroll
    for (int nb = 0; nb < 2; nb++) {
        float rs = l_lane[nb];
        rs += __shfl_xor(rs, 16);
        rs += __shfl_xor(rs, 32);
        int qrow = q0 + w * 32 + nb * 16 + l16;
        if (quad == 0)
            lp[(size_t)split * BSH_ + ((size_t)b * S_ + qrow) * H_ + h] = rs;
        const size_t rbase = base + (size_t)qrow * D_;
#pragma unroll
        for (int dblk = 0; dblk < 4; dblk++)
            *(v4f*)&Ops[rbase + dblk * 16 + quad * 4] = o[nb][dblk];
    }
}

extern "C" void kernel_launch(void* const* d_in, const int* in_sizes, int n_in,
                              void* d_out, int out_size, void* d_ws, size_t ws_size,
                              hipStream_t stream) {
    const float* query = (const float*)d_in[0];
    const float* key   = (const float*)d_in[1];
    const float* value = (const float*)d_in[2];
    const float* Wq    = (const float*)d_in[3];
    const float* bq    = (const float*)d_in[4];
    const float* Wo    = (const float*)d_in[5];
    const float* bo    = (const float*)d_in[6];
    float* out = (float*)d_out;

    _Float16* ws = (_Float16*)d_ws;
    _Float16* Qh = ws;                                   // [B,S,D] f16 (dead after flash)
    _Float16* Kh = ws + (size_t)SZ_;                     // [B,S,D] f16
    _Float16* VT = ws + 2 * (size_t)SZ_;                 // [B,H,HD,S] f16 (permuted)
    _Float16* Wt = ws + 3 * (size_t)SZ_;                 // 2x[4 nt][8 kc][128x64 swz] f16
    _Float16* Xh = ws + 3 * (size_t)SZ_ + 2 * (size_t)WSZ_;  // 3x[64 mt][8 kc][128x64 swz] f16 (dead after proj)
    float*    Op = (float*)Xh;                           // 2x[B,S,D] f32 (aliases Xh)
    float*    lp = Op + 2 * (size_t)SZ_;                 // 2x[B,S,H] f32
    _Float16* Ah = Qh;                                   // [64 mt][8 kc][128x64 swz] f16 (aliases Qh)

    wtrans_kernel<<<dim3(8, 4, 2), 256, 0, stream>>>(Wq, Wo, Wt);
    convert_f16<<<dim3(8, 64, 3), 256, 0, stream>>>(query, key, value, Xh);
    proj_mfma<<<dim3(4, 64, 3), 256, 0, stream>>>(Xh, Wt, bq, Qh, Kh, VT);
    flash_attn_f16<<<dim3(S_ / 128, H_, B_ * 2), 256, 0, stream>>>(Qh, Kh, VT, Op, lp);
    combine_kernel<<<dim3(8, 64), 256, 0, stream>>>(Op, lp, Ah);
    outproj_mfma<<<dim3(4, 64), 256, 0, stream>>>(Ah, Wt, bo, out);
}

// Round 5
// 201.335 us; speedup vs baseline: 1.4034x; 1.0033x over previous
//
#include <hip/hip_runtime.h>
#include <math.h>

#define B_ 4
#define S_ 2048
#define D_ 512
#define H_ 8
#define HD_ 64
#define SZ_ (B_ * S_ * D_)
#define WSZ_ (D_ * D_)   // 262144
#define BSH_ (B_ * S_ * H_)

// 0.125 * log2(e): folds the 1/sqrt(64) score scale and exp->exp2 into Qh.
#define QSCALE_ 0.18033688011112042f

typedef _Float16 v4h __attribute__((ext_vector_type(4)));
typedef _Float16 v8h __attribute__((ext_vector_type(8)));
typedef float    v4f __attribute__((ext_vector_type(4)));

// Async global->LDS, 16B per lane. LDS dest must be wave-uniform base
// (HW adds lane*16); global source is per-lane.
__device__ __forceinline__ void gload16(const void* g, void* l) {
    __builtin_amdgcn_global_load_lds((__attribute__((address_space(1))) void*)g,
                                     (__attribute__((address_space(3))) void*)l,
                                     16, 0, 0);
}

__device__ __forceinline__ v8h pack8(v4f a, v4f b) {
    return __builtin_shufflevector(__builtin_convertvector(a, v4h),
                                   __builtin_convertvector(b, v4h),
                                   0, 1, 2, 3, 4, 5, 6, 7);
}

// ---------------------------------------------------------------------------
// W[k][n] fp32 -> 16KB swizzled f16 blocks, 128 n-rows x 64 k each.
// block(mat, nt4, kc8): f16 idx r*64 + s*8 + j = W[kc*64 + (s^(r&7))*8 + j][nt*128 + r]
// ---------------------------------------------------------------------------
__global__ __launch_bounds__(256) void wtrans_kernel(const float* __restrict__ Wq,
                                                     const float* __restrict__ Wo,
                                                     _Float16* __restrict__ Wt) {
    __shared__ float Ts[64][132];
    const int kc = blockIdx.x, nt = blockIdx.y, mat = blockIdx.z;
    const float* W = mat ? Wo : Wq;
    const int k0 = kc * 64, n0 = nt * 128;
    const int t = threadIdx.x;
#pragma unroll
    for (int i = 0; i < 8; i++) {
        int s2 = t + i * 256;
        int kk = s2 >> 5, nc = (s2 & 31) * 4;
        *(float4*)&Ts[kk][nc] = *(const float4*)&W[(size_t)(k0 + kk) * 512 + n0 + nc];
    }
    __syncthreads();
    _Float16* blk = Wt + (((size_t)mat * 4 + nt) * 8 + kc) * 8192;
#pragma unroll
    for (int i = 0; i < 4; i++) {
        int s2 = t + i * 256;
        int r = s2 >> 3, s = s2 & 7;
        int kl = (s ^ (r & 7)) * 8;
        v8h p;
#pragma unroll
        for (int j = 0; j < 8; j++) p[j] = (_Float16)Ts[kl + j][r];
        *(v8h*)&blk[r * 64 + s * 8] = p;
    }
}

// ---------------------------------------------------------------------------
// q/k/v fp32 -> Xh f16 in blocked-swizzled layout [z][mt64][kc8][128x64].
// ---------------------------------------------------------------------------
__global__ __launch_bounds__(256) void convert_f16(const float* __restrict__ q,
                                                   const float* __restrict__ k,
                                                   const float* __restrict__ v,
                                                   _Float16* __restrict__ Xh) {
    const int kc = blockIdx.x, mt = blockIdx.y, z = blockIdx.z;
    const float* X = (z == 0) ? q : ((z == 1) ? k : v);
    _Float16* blk = Xh + (size_t)z * SZ_ + ((size_t)mt * 8 + kc) * 8192;
    const int t = threadIdx.x;
#pragma unroll
    for (int i = 0; i < 4; i++) {
        int s2 = t + i * 256;
        int r = s2 >> 3, s = s2 & 7;
        const float* src = X + (size_t)(mt * 128 + r) * 512 + kc * 64 + s * 8;
        *(v8h*)&blk[r * 64 + ((s ^ (r & 7)) * 8)] =
            pack8(*(const v4f*)src, *(const v4f*)(src + 4));
    }
}

// ---------------------------------------------------------------------------
// Split-K combine (O1+O2)*1/l -> Ah f16, blocked-swizzled [mt64][kc8][128x64].
// ---------------------------------------------------------------------------
__global__ __launch_bounds__(256) void combine_kernel(const float* __restrict__ Op,
                                                      const float* __restrict__ lp,
                                                      _Float16* __restrict__ Ah) {
    const int kc = blockIdx.x, mt = blockIdx.y;
    _Float16* blk = Ah + ((size_t)mt * 8 + kc) * 8192;
    const int t = threadIdx.x;
#pragma unroll
    for (int i = 0; i < 4; i++) {
        int s2 = t + i * 256;
        int r = s2 >> 3, s = s2 & 7;
        size_t row = (size_t)mt * 128 + r;
        const float* p = Op + row * 512 + kc * 64 + s * 8;
        const float* p2 = p + SZ_;
        float linv = __builtin_amdgcn_rcpf(lp[row * 8 + kc] + lp[BSH_ + row * 8 + kc]);
        v4f sa = (*(const v4f*)p + *(const v4f*)p2) * linv;
        v4f sb = (*(const v4f*)(p + 4) + *(const v4f*)(p2 + 4)) * linv;
        *(v8h*)&blk[r * 64 + ((s ^ (r & 7)) * 8)] = pack8(sa, sb);
    }
}

// ---------------------------------------------------------------------------
// m97-shaped pure-f16 GEMM. 128x128 tile, BK=64, 4 waves (2x2), both operands
// via global_load_lds from pre-swizzled blocks, 32KB LDS, 2 barriers/iter.
// z in {0,1,2} -> Qh (pre-scaled) / Kh / VT [B,H,HD,S(permuted)].
// ---------------------------------------------------------------------------
__global__ __launch_bounds__(256) void proj_mfma(const _Float16* __restrict__ Xh,
                                                 const _Float16* __restrict__ Wt,
                                                 const float* __restrict__ bq,
                                                 _Float16* __restrict__ Qh,
                                                 _Float16* __restrict__ Kh,
                                                 _Float16* __restrict__ VT) {
    __shared__ __align__(16) _Float16 As[8192];
    __shared__ __align__(16) _Float16 Bs[8192];
    const int nt = blockIdx.x, mt = blockIdx.y, z = blockIdx.z;
    const int n0 = nt * 128, m0 = mt * 128;
    const int t = threadIdx.x, lane = t & 63, w = t >> 6;
    const int wm = w >> 1, wn = w & 1;
    const int quad = lane >> 4, l16 = lane & 15;

    const _Float16* Ab = Xh + (size_t)z * SZ_ + ((size_t)mt * 8) * 8192 + w * 512 + lane * 8;
    const _Float16* Bb = Wt + ((size_t)nt * 8) * 8192 + w * 512 + lane * 8;
    _Float16* Ad = As + w * 512;
    _Float16* Bd = Bs + w * 512;

    v4f acc[4][4];
#pragma unroll
    for (int mi = 0; mi < 4; mi++)
#pragma unroll
        for (int ni = 0; ni < 4; ni++) acc[mi][ni] = (v4f)0.f;

    for (int kc = 0; kc < 8; ++kc) {
        __syncthreads();   // prev iter's frag reads complete
#pragma unroll
        for (int i = 0; i < 4; i++) {
            gload16(Ab + kc * 8192 + i * 2048, Ad + i * 2048);
            gload16(Bb + kc * 8192 + i * 2048, Bd + i * 2048);
        }
        __syncthreads();   // vmcnt drained -> LDS tiles ready

#pragma unroll
        for (int ks = 0; ks < 2; ++ks) {
            const int sxx = (ks * 32 + quad * 8) ^ ((l16 & 7) * 8);
            v8h af[4], bf[4];
#pragma unroll
            for (int mi = 0; mi < 4; mi++)
                af[mi] = *(const v8h*)&As[(wm * 64 + mi * 16 + l16) * 64 + sxx];
#pragma unroll
            for (int ni = 0; ni < 4; ni++)
                bf[ni] = *(const v8h*)&Bs[(wn * 64 + ni * 16 + l16) * 64 + sxx];
#pragma unroll
            for (int mi = 0; mi < 4; mi++)
#pragma unroll
                for (int ni = 0; ni < 4; ni++)
                    acc[mi][ni] = __builtin_amdgcn_mfma_f32_16x16x32_f16(af[mi], bf[ni], acc[mi][ni], 0, 0, 0);
        }
    }

    if (z < 2) {
        _Float16* Y = z ? Kh : Qh;
        const float sc = z ? 1.f : QSCALE_;
#pragma unroll
        for (int mi = 0; mi < 4; mi++) {
            int mb = m0 + wm * 64 + mi * 16 + quad * 4;
#pragma unroll
            for (int ni = 0; ni < 4; ni++) {
                int n = n0 + wn * 64 + ni * 16 + l16;
                float bj = bq[n];
#pragma unroll
                for (int r = 0; r < 4; r++)
                    Y[(size_t)(mb + r) * 512 + n] = (_Float16)((acc[mi][ni][r] + bj) * sc);
            }
        }
    } else {
#pragma unroll
        for (int mi = 0; mi < 4; mi++) {
            int tile0 = (m0 & 2047) + wm * 64;
            int pos = tile0 + (mi >> 1) * 32 + quad * 8 + (mi & 1) * 4;
            int b = m0 >> 11;
#pragma unroll
            for (int ni = 0; ni < 4; ni++) {
                int n = n0 + wn * 64 + ni * 16 + l16;
                int h = n >> 6, dd = n & 63;
                float bj = bq[n];
                v4h pk;
#pragma unroll
                for (int r = 0; r < 4; r++) pk[r] = (_Float16)(acc[mi][ni][r] + bj);
                *(v4h*)&VT[(((size_t)b * H_ + h) * HD_ + dd) * S_ + pos] = pk;
            }
        }
    }
}

// ---------------------------------------------------------------------------
// outproj: identical m97-shaped GEMM; A = Ah (combine output), B = Wo panel.
// ---------------------------------------------------------------------------
__global__ __launch_bounds__(256) void outproj_mfma(const _Float16* __restrict__ Ah,
                                                    const _Float16* __restrict__ Wt,
                                                    const float* __restrict__ bo,
                                                    float* __restrict__ out) {
    __shared__ __align__(16) _Float16 As[8192];
    __shared__ __align__(16) _Float16 Bs[8192];
    const int nt = blockIdx.x, mt = blockIdx.y;
    const int n0 = nt * 128, m0 = mt * 128;
    const int t = threadIdx.x, lane = t & 63, w = t >> 6;
    const int wm = w >> 1, wn = w & 1;
    const int quad = lane >> 4, l16 = lane & 15;

    const _Float16* Ab = Ah + ((size_t)mt * 8) * 8192 + w * 512 + lane * 8;
    const _Float16* Bb = Wt + (size_t)(4 + nt) * 8 * 8192 + w * 512 + lane * 8;
    _Float16* Ad = As + w * 512;
    _Float16* Bd = Bs + w * 512;

    v4f acc[4][4];
#pragma unroll
    for (int mi = 0; mi < 4; mi++)
#pragma unroll
        for (int ni = 0; ni < 4; ni++) acc[mi][ni] = (v4f)0.f;

    for (int kc = 0; kc < 8; ++kc) {
        __syncthreads();
#pragma unroll
        for (int i = 0; i < 4; i++) {
            gload16(Ab + kc * 8192 + i * 2048, Ad + i * 2048);
            gload16(Bb + kc * 8192 + i * 2048, Bd + i * 2048);
        }
        __syncthreads();

#pragma unroll
        for (int ks = 0; ks < 2; ++ks) {
            const int sxx = (ks * 32 + quad * 8) ^ ((l16 & 7) * 8);
            v8h af[4], bf[4];
#pragma unroll
            for (int mi = 0; mi < 4; mi++)
                af[mi] = *(const v8h*)&As[(wm * 64 + mi * 16 + l16) * 64 + sxx];
#pragma unroll
            for (int ni = 0; ni < 4; ni++)
                bf[ni] = *(const v8h*)&Bs[(wn * 64 + ni * 16 + l16) * 64 + sxx];
#pragma unroll
            for (int mi = 0; mi < 4; mi++)
#pragma unroll
                for (int ni = 0; ni < 4; ni++)
                    acc[mi][ni] = __builtin_amdgcn_mfma_f32_16x16x32_f16(af[mi], bf[ni], acc[mi][ni], 0, 0, 0);
        }
    }

#pragma unroll
    for (int mi = 0; mi < 4; mi++) {
        int mb = m0 + wm * 64 + mi * 16 + quad * 4;
#pragma unroll
        for (int ni = 0; ni < 4; ni++) {
            int n = n0 + wn * 64 + ni * 16 + l16;
            float bj = bo[n];
#pragma unroll
            for (int r = 0; r < 4; r++)
                out[(size_t)(mb + r) * 512 + n] = acc[mi][ni][r] + bj;
        }
    }
}

// ---------------------------------------------------------------------------
// R15 flash: QBLK 256 (4 nb per wave: LDS reads per MFMA halved — flash was
// LDS-pipe-bound at 601 TF, MFMA pipe only ~7%), PV via 16x16x32 (vf2 is the
// exact x32 A-frag; concat(pf[2p],pf[2p+1]) is the exact x32 B-frag under the
// VT key-permutation). Grid (8,8,8) = 512 blocks. Layouts/staging unchanged.
// ---------------------------------------------------------------------------
__global__ __launch_bounds__(256) void flash_attn_f16(const _Float16* __restrict__ Qh,
                                                      const _Float16* __restrict__ Kh,
                                                      const _Float16* __restrict__ VT,
                                                      float* __restrict__ Op,
                                                      float* __restrict__ lp) {
    __shared__ _Float16 Ks[128 * 72];    // [key][d], pad 72
    __shared__ _Float16 Vs[64 * 136];    // [d][pos], pad 136

    const int t     = threadIdx.x;
    const int lane  = t & 63;
    const int w     = t >> 6;
    const int quad  = lane >> 4;
    const int l16   = lane & 15;
    const int q0    = blockIdx.x * 256;
    const int h     = blockIdx.y;
    const int b     = blockIdx.z >> 1;
    const int split = blockIdx.z & 1;

    const size_t base  = (size_t)b * S_ * D_ + (size_t)h * HD_;
    const size_t vbase = ((size_t)b * H_ + h) * HD_ * (size_t)S_;

    v8h qf[4][2];
#pragma unroll
    for (int nb = 0; nb < 4; nb++) {
        const _Float16* qrow = Qh + base + (size_t)(q0 + w * 64 + nb * 16 + l16) * D_;
        qf[nb][0] = *(const v8h*)(qrow + quad * 8);
        qf[nb][1] = *(const v8h*)(qrow + 32 + quad * 8);
    }

    v4f o[4][4];
#pragma unroll
    for (int nb = 0; nb < 4; nb++)
#pragma unroll
        for (int i = 0; i < 4; i++) o[nb][i] = (v4f)0.f;
    float l_lane[4] = {0.f, 0.f, 0.f, 0.f};

    const int kbeg = split * (S_ / 2);
    const int kend = kbeg + S_ / 2;

    v8h kv[4], vv[4];
#define LOADKV(kk)                                                             \
    do {                                                                       \
        _Pragma("unroll") for (int i = 0; i < 4; i++) {                        \
            int c = t + i * 256;                                               \
            kv[i] = *(const v8h*)(Kh + base + (size_t)((kk) + (c >> 3)) * D_ + (c & 7) * 8); \
            vv[i] = *(const v8h*)(VT + vbase + (size_t)(c >> 4) * S_ + (kk) + (c & 15) * 8); \
        }                                                                      \
    } while (0)

    LOADKV(kbeg);

    for (int kk0 = kbeg; kk0 < kend; kk0 += 128) {
        __syncthreads();
#pragma unroll
        for (int i = 0; i < 4; i++) {
            int c = t + i * 256;
            *(v8h*)&Ks[(c >> 3) * 72 + (c & 7) * 8] = kv[i];
            *(v8h*)&Vs[(c >> 4) * 136 + (c & 15) * 8] = vv[i];
        }
        __syncthreads();

        if (kk0 + 128 < kend) LOADKV(kk0 + 128);

#pragma unroll
        for (int hh = 0; hh < 2; hh++) {
            v4h pf[4][4];
            // QK^T + exp, per-mb to cap sc live range
#pragma unroll
            for (int mb = 0; mb < 4; mb++) {
                v4f sc[4];
#pragma unroll
                for (int nb = 0; nb < 4; nb++) sc[nb] = (v4f)0.f;
#pragma unroll
                for (int ks = 0; ks < 2; ks++) {
                    v8h ak = *(const v8h*)&Ks[(hh * 64 + mb * 16 + l16) * 72 + ks * 32 + quad * 8];
#pragma unroll
                    for (int nb = 0; nb < 4; nb++)
                        sc[nb] = __builtin_amdgcn_mfma_f32_16x16x32_f16(ak, qf[nb][ks], sc[nb], 0, 0, 0);
                }
#pragma unroll
                for (int nb = 0; nb < 4; nb++) {
                    v4f pv;
#pragma unroll
                    for (int r = 0; r < 4; r++) pv[r] = __builtin_amdgcn_exp2f(sc[nb][r]);
                    pf[mb][nb] = __builtin_convertvector(pv, v4h);
                    l_lane[nb] += (pv[0] + pv[1]) + (pv[2] + pv[3]);
                }
            }

            // PV: one 16x16x32 per (p, dblk, nb)
#pragma unroll
            for (int p = 0; p < 2; p++) {
#pragma unroll
                for (int dblk = 0; dblk < 4; dblk++) {
                    v8h vf2 = *(const v8h*)&Vs[(dblk * 16 + l16) * 136 + hh * 64 + p * 32 + quad * 8];
#pragma unroll
                    for (int nb = 0; nb < 4; nb++) {
                        v8h pf8 = __builtin_shufflevector(pf[2 * p][nb], pf[2 * p + 1][nb],
                                                          0, 1, 2, 3, 4, 5, 6, 7);
                        o[nb][dblk] = __builtin_amdgcn_mfma_f32_16x16x32_f16(vf2, pf8, o[nb][dblk], 0, 0, 0);
                    }
                }
            }
        }
    }
#undef LOADKV

    float* Ops = Op + (size_t)split * SZ_;
#pragma unroll
    for (int nb = 0; nb < 4; nb++) {
        float rs = l_lane[nb];
        rs += __shfl_xor(rs, 16);
        rs += __shfl_xor(rs, 32);
        int qrow = q0 + w * 64 + nb * 16 + l16;
        if (quad == 0)
            lp[(size_t)split * BSH_ + ((size_t)b * S_ + qrow) * H_ + h] = rs;
        const size_t rbase = base + (size_t)qrow * D_;
#pragma unroll
        for (int dblk = 0; dblk < 4; dblk++)
            *(v4f*)&Ops[rbase + dblk * 16 + quad * 4] = o[nb][dblk];
    }
}

extern "C" void kernel_launch(void* const* d_in, const int* in_sizes, int n_in,
                              void* d_out, int out_size, void* d_ws, size_t ws_size,
                              hipStream_t stream) {
    const float* query = (const float*)d_in[0];
    const float* key   = (const float*)d_in[1];
    const float* value = (const float*)d_in[2];
    const float* Wq    = (const float*)d_in[3];
    const float* bq    = (const float*)d_in[4];
    const float* Wo    = (const float*)d_in[5];
    const float* bo    = (const float*)d_in[6];
    float* out = (float*)d_out;

    _Float16* ws = (_Float16*)d_ws;
    _Float16* Qh = ws;                                   // [B,S,D] f16 (dead after flash)
    _Float16* Kh = ws + (size_t)SZ_;                     // [B,S,D] f16
    _Float16* VT = ws + 2 * (size_t)SZ_;                 // [B,H,HD,S] f16 (permuted)
    _Float16* Wt = ws + 3 * (size_t)SZ_;                 // 2x[4 nt][8 kc][128x64 swz] f16
    _Float16* Xh = ws + 3 * (size_t)SZ_ + 2 * (size_t)WSZ_;  // 3x[64 mt][8 kc][128x64 swz] f16 (dead after proj)
    float*    Op = (float*)Xh;                           // 2x[B,S,D] f32 (aliases Xh)
    float*    lp = Op + 2 * (size_t)SZ_;                 // 2x[B,S,H] f32
    _Float16* Ah = Qh;                                   // [64 mt][8 kc][128x64 swz] f16 (aliases Qh)

    wtrans_kernel<<<dim3(8, 4, 2), 256, 0, stream>>>(Wq, Wo, Wt);
    convert_f16<<<dim3(8, 64, 3), 256, 0, stream>>>(query, key, value, Xh);
    proj_mfma<<<dim3(4, 64, 3), 256, 0, stream>>>(Xh, Wt, bq, Qh, Kh, VT);
    flash_attn_f16<<<dim3(S_ / 256, H_, B_ * 2), 256, 0, stream>>>(Qh, Kh, VT, Op, lp);
    combine_kernel<<<dim3(8, 64), 256, 0, stream>>>(Op, lp, Ah);
    outproj_mfma<<<dim3(4, 64), 256, 0, stream>>>(Ah, Wt, bo, out);
}